// Round 3
// baseline (280.109 us; speedup 1.0000x reference)
//
#include <hip/hip_runtime.h>

#define N_IMG 32
#define C_DIM 64
#define HW_SZ 4096
#define K_CODES 512
#define N_TOK (N_IMG * HW_SZ)   // 131072

// ws layout (float offsets):
//   [0, 512)        cnt accumulator
//   [512, 33280)    avg accumulator [512][64]
//   [33280]         loss accumulator
//   [33536, 34048)  enorm[512]
//   [34048, ...)    idx[int, 131072]

__global__ void k_prep(const float* __restrict__ emb, float* __restrict__ enorm) {
    int k = blockIdx.x * blockDim.x + threadIdx.x;
    if (k < K_CODES) {
        const float* e = emb + k * 64;
        float d0 = 0.f, d1 = 0.f, d2 = 0.f, d3 = 0.f;
#pragma unroll
        for (int c = 0; c < 64; c += 4) {
            d0 = fmaf(e[c], e[c], d0);
            d1 = fmaf(e[c + 1], e[c + 1], d1);
            d2 = fmaf(e[c + 2], e[c + 2], d2);
            d3 = fmaf(e[c + 3], e[c + 3], d3);
        }
        enorm[k] = (d0 + d1) + (d2 + d3);
    }
}

// 1 token/thread, no LDS. Code vectors are read at wave-uniform addresses
// directly from global -> compiler emits s_load into SGPRs (scalar cache,
// L2-resident 128KB codebook). Inner op: v_fma_f32 v,v,s,v. kk unrolled x2
// for 8 independent FMA chains + s_load pipelining.
__global__ __launch_bounds__(256) void k_main(const float* __restrict__ x,
                                              const float* __restrict__ emb,
                                              const float* __restrict__ enorm,
                                              float* __restrict__ qout,
                                              int* __restrict__ idx_out,
                                              float* __restrict__ loss_acc) {
    __shared__ float red[4];

    int tid = threadIdx.x;
    int t = blockIdx.x * 256 + tid;
    int n = t >> 12;
    int hw = t & 4095;
    const float* xp = x + (size_t)n * C_DIM * HW_SZ;

    float xv[64];
#pragma unroll
    for (int c = 0; c < 64; ++c) xv[c] = xp[(size_t)c * HW_SZ + hw];

    float sxx;
    {
        float d0 = 0.f, d1 = 0.f, d2 = 0.f, d3 = 0.f;
#pragma unroll
        for (int c = 0; c < 64; c += 4) {
            d0 = fmaf(xv[c], xv[c], d0);
            d1 = fmaf(xv[c + 1], xv[c + 1], d1);
            d2 = fmaf(xv[c + 2], xv[c + 2], d2);
            d3 = fmaf(xv[c + 3], xv[c + 3], d3);
        }
        sxx = (d0 + d1) + (d2 + d3);
    }

    float best = 3.402823466e38f;
    int bestk = 0;

    for (int kk = 0; kk < K_CODES; kk += 2) {
        const float* e0p = emb + (size_t)kk * 64;
        const float* e1p = e0p + 64;
        float a0 = 0.f, a1 = 0.f, a2 = 0.f, a3 = 0.f;
        float b0 = 0.f, b1 = 0.f, b2 = 0.f, b3 = 0.f;
#pragma unroll
        for (int c = 0; c < 64; c += 4) {
            a0 = fmaf(xv[c], e0p[c], a0);         b0 = fmaf(xv[c], e1p[c], b0);
            a1 = fmaf(xv[c + 1], e0p[c + 1], a1); b1 = fmaf(xv[c + 1], e1p[c + 1], b1);
            a2 = fmaf(xv[c + 2], e0p[c + 2], a2); b2 = fmaf(xv[c + 2], e1p[c + 2], b2);
            a3 = fmaf(xv[c + 3], e0p[c + 3], a3); b3 = fmaf(xv[c + 3], e1p[c + 3], b3);
        }
        float dota = (a0 + a1) + (a2 + a3);
        float dotb = (b0 + b1) + (b2 + b3);
        float sa = (sxx + enorm[kk]) - 2.0f * dota;
        float sb = (sxx + enorm[kk + 1]) - 2.0f * dotb;
        if (sa < best) { best = sa; bestk = kk; }
        if (sb < best) { best = sb; bestk = kk + 1; }
    }

    idx_out[t] = bestk;

    const float* e = emb + (size_t)bestk * 64;
    float* qp = qout + (size_t)n * C_DIM * HW_SZ;
    float l0 = 0.f, l1 = 0.f, l2 = 0.f, l3 = 0.f;
#pragma unroll
    for (int c = 0; c < 64; c += 4) {
        float e0 = e[c], e1 = e[c + 1], e2 = e[c + 2], e3 = e[c + 3];
        qp[(size_t)c * HW_SZ + hw] = e0;
        qp[(size_t)(c + 1) * HW_SZ + hw] = e1;
        qp[(size_t)(c + 2) * HW_SZ + hw] = e2;
        qp[(size_t)(c + 3) * HW_SZ + hw] = e3;
        float f0 = xv[c] - e0, f1 = xv[c + 1] - e1, f2 = xv[c + 2] - e2, f3 = xv[c + 3] - e3;
        l0 = fmaf(f0, f0, l0);
        l1 = fmaf(f1, f1, l1);
        l2 = fmaf(f2, f2, l2);
        l3 = fmaf(f3, f3, l3);
    }
    float lp = (l0 + l1) + (l2 + l3);
#pragma unroll
    for (int off = 32; off; off >>= 1) lp += __shfl_down(lp, off);
    if ((tid & 63) == 0) red[tid >> 6] = lp;
    __syncthreads();
    if (tid == 0) {
        float s = (red[0] + red[1]) + (red[2] + red[3]);
        atomicAdd(loss_acc, s);
    }
}

// grid = (32 images) x (8 channel-groups) = 256 blocks, 1024 threads.
// LDS acc [512][9] (pad 9: coprime to 32 banks -> random-k atomics spread).
__global__ __launch_bounds__(1024) void k_seg(const float* __restrict__ x,
                                              const int* __restrict__ idx,
                                              float* __restrict__ cnt_g,
                                              float* __restrict__ avg_g) {
    __shared__ float acc[K_CODES * 9];
    __shared__ float cnt[K_CODES];
    int tid = threadIdx.x;
    int n = blockIdx.x >> 3;
    int cg = blockIdx.x & 7;

    for (int i = tid; i < K_CODES * 9; i += 1024) acc[i] = 0.f;
    if (cg == 0 && tid < K_CODES) cnt[tid] = 0.f;
    __syncthreads();

    const float* xp = x + (size_t)n * C_DIM * HW_SZ + (size_t)(cg * 8) * HW_SZ;
    const int* ip = idx + n * HW_SZ;

#pragma unroll
    for (int p = 0; p < 4; ++p) {
        int hw = p * 1024 + tid;
        int k = ip[hw];
        if (cg == 0) atomicAdd(&cnt[k], 1.0f);
        float* row = acc + k * 9;
#pragma unroll
        for (int j = 0; j < 8; ++j) {
            atomicAdd(&row[j], xp[(size_t)j * HW_SZ + hw]);
        }
    }
    __syncthreads();

    for (int i = tid; i < K_CODES * 8; i += 1024) {
        int k = i >> 3, j = i & 7;
        atomicAdd(&avg_g[k * 64 + cg * 8 + j], acc[k * 9 + j]);
    }
    if (cg == 0 && tid < K_CODES) atomicAdd(&cnt_g[tid], cnt[tid]);
}

__global__ void k_fin(const float* __restrict__ cs_in, const float* __restrict__ avg_in,
                      const float* __restrict__ cnt, const float* __restrict__ avgacc,
                      const float* __restrict__ loss_acc,
                      float* __restrict__ loss_out, float* __restrict__ emb_out,
                      float* __restrict__ cs_out, float* __restrict__ avg_out) {
    int i = blockIdx.x * 256 + threadIdx.x;
    if (i >= K_CODES * 64) return;
    int k = i >> 6, c = i & 63;
    float ncs = cs_in[k] * 0.99f + 0.01f * cnt[k];
    float nav = avg_in[i] * 0.99f + 0.01f * avgacc[i];
    avg_out[i] = nav;
    emb_out[i] = nav / (ncs + 1e-5f);
    if (c == 0) cs_out[k] = ncs;
    if (i == 0) loss_out[0] = loss_acc[0] * (1.0f / 8388608.0f);
}

extern "C" void kernel_launch(void* const* d_in, const int* in_sizes, int n_in,
                              void* d_out, int out_size, void* d_ws, size_t ws_size,
                              hipStream_t stream) {
    (void)in_sizes; (void)n_in; (void)out_size; (void)ws_size;
    const float* x   = (const float*)d_in[0];
    const float* emb = (const float*)d_in[1];
    const float* cs  = (const float*)d_in[2];
    const float* avg = (const float*)d_in[3];

    float* out      = (float*)d_out;
    float* qout     = out;
    float* loss_out = out + 8388608;
    float* emb_out  = loss_out + 1;
    float* cs_out   = emb_out + 32768;
    float* avg_out  = cs_out + 512;

    float* wsf      = (float*)d_ws;
    float* cnt_acc  = wsf;
    float* avg_acc  = wsf + 512;
    float* loss_acc = wsf + 33280;
    float* enorm    = wsf + 33536;
    int*   idx      = (int*)(wsf + 34048);

    hipMemsetAsync(d_ws, 0, 33281 * sizeof(float), stream);
    k_prep<<<2, 256, 0, stream>>>(emb, enorm);
    k_main<<<N_TOK / 256, 256, 0, stream>>>(x, emb, enorm, qout, idx, loss_acc);
    k_seg<<<256, 1024, 0, stream>>>(x, idx, cnt_acc, avg_acc);
    k_fin<<<128, 256, 0, stream>>>(cs, avg, cnt_acc, avg_acc, loss_acc,
                                   loss_out, emb_out, cs_out, avg_out);
}

// Round 4
// 179.867 us; speedup vs baseline: 1.5573x; 1.5573x over previous
//
#include <hip/hip_runtime.h>

#define HW 4096
#define KC 512

typedef __attribute__((ext_vector_type(8))) short s16x8;
typedef __attribute__((ext_vector_type(16))) float f32x16;

__device__ inline short f2bf(float f) {          // RTNE float->bf16
    unsigned int u = __builtin_bit_cast(unsigned int, f);
    unsigned int lsb = (u >> 16) & 1u;
    u += 0x7fffu + lsb;
    return (short)(u >> 16);
}
__device__ inline float bf2f(short h) {
    unsigned int u = ((unsigned int)(unsigned short)h) << 16;
    return __builtin_bit_cast(float, u);
}

// ws byte layout:
//   0       cnt f32[512]                  (zeroed)
//   2048    avg f32[32768]                (zeroed)
//   133120  loss f32[1]                   (zeroed)
//   133136  en f32[512]
//   135184  ehfrag short[16*5*64*8]  80KB (codes hi + en hi/lo cols, K=80)
//   217104  elfrag short[16*4*64*8]  64KB (codes lo, K=64)
//   282640  idx u16[131072]
#define WS_EN    133136
#define WS_EHF   135184
#define WS_ELF   217104
#define WS_IDX   282640

__global__ void k_prep_en(const float* __restrict__ emb, float* __restrict__ en) {
    int m = blockIdx.x * 256 + threadIdx.x;
    if (m >= KC) return;
    const float* e = emb + m * 64;
    float d0 = 0.f, d1 = 0.f, d2 = 0.f, d3 = 0.f;
#pragma unroll
    for (int c = 0; c < 64; c += 4) {
        d0 = fmaf(e[c], e[c], d0);
        d1 = fmaf(e[c + 1], e[c + 1], d1);
        d2 = fmaf(e[c + 2], e[c + 2], d2);
        d3 = fmaf(e[c + 3], e[c + 3], d3);
    }
    en[m] = (d0 + d1) + (d2 + d3);
}

// Build pre-swizzled A-fragments (32x32x16 layout: m=lane&31, k=(lane>>5)*8+j).
__global__ void k_prep_frag(const float* __restrict__ emb, const float* __restrict__ en,
                            short* __restrict__ ehf, short* __restrict__ elf) {
    int t = blockIdx.x * 256 + threadIdx.x;   // 0..4095
    int m = t >> 3, ko = t & 7;
    int mt = m >> 5, ks = ko >> 1;
    int lane = (m & 31) + 32 * (ko & 1);
    s16x8 hv, lv;
#pragma unroll
    for (int j = 0; j < 8; ++j) {
        float v = emb[m * 64 + ko * 8 + j];
        short h = f2bf(v);
        hv[j] = h;
        lv[j] = f2bf(v - bf2f(h));
    }
    ((s16x8*)ehf)[(mt * 5 + ks) * 64 + lane] = hv;
    ((s16x8*)elf)[(mt * 4 + ks) * 64 + lane] = lv;

    // ks=4 block of ehf: k=64 -> en_hi, k=65 -> en_lo, rest 0. One u32 per thread.
    int e2 = t * 2;
    int mt2 = e2 >> 9;
    int lane2 = (e2 >> 3) & 63;
    int j2 = e2 & 7;
    unsigned int val = 0;
    if (lane2 < 32 && j2 == 0) {
        float ev = en[mt2 * 32 + (lane2 & 31)];
        short eh_ = f2bf(ev);
        short el_ = f2bf(ev - bf2f(eh_));
        val = ((unsigned int)(unsigned short)eh_) | (((unsigned int)(unsigned short)el_) << 16);
    }
    *(unsigned int*)(ehf + ((size_t)(mt2 * 5 + 4) * 64 + lane2) * 8 + j2) = val;
}

__device__ inline void merge2(float& s1, int& i1, float& s2, int& i2,
                              float os1, int oi1, float os2, int oi2) {
    bool ob = (os1 < s1) || (os1 == s1 && oi1 < i1);
    float n1s = ob ? os1 : s1;  int n1i = ob ? oi1 : i1;
    float ls  = ob ? s1  : os1; int li  = ob ? i1  : oi1;  // losing first
    float ws  = ob ? os2 : s2;  int wi  = ob ? oi2 : i2;   // winner's second
    bool b2 = (ls < ws) || (ls == ws && li < wi);
    s1 = n1s; i1 = n1i;
    s2 = b2 ? ls : ws; i2 = b2 ? li : wi;
}

// Block: 256 threads = 4 waves, 256 tokens. Each wave: 64 tokens x 512 codes.
// score_rel = en - 2*x.e accumulated via 13 MFMA/tile (xh*eh80 + xh*el + xl*eh).
__global__ __launch_bounds__(256) void k_main(const float* __restrict__ x,
                                              const short* __restrict__ ehf,
                                              const short* __restrict__ elf,
                                              const float* __restrict__ en,
                                              const float* __restrict__ emb,
                                              float* __restrict__ qout,
                                              unsigned short* __restrict__ idx_out,
                                              float* __restrict__ loss_acc) {
    __shared__ short shH[8 * 5 * 64 * 8];  // 40KB  [g][ks][lane][j]
    __shared__ short shL[8 * 4 * 64 * 8];  // 32KB

    int tid = threadIdx.x;
    int tb = blockIdx.x * 256;
    int n = tb >> 12, hwb = tb & 4095;
    const float* xp = x + (size_t)n * 64 * HW;

    // ---- stage x~ = -2x as hi/lo bf16 B-fragments ----
    int g = tid >> 5, l5 = tid & 31;
#pragma unroll
    for (int cb = 0; cb < 8; ++cb) {
        s16x8 hv, lv;
#pragma unroll
        for (int j = 0; j < 8; ++j) {
            int c = cb * 8 + j;
            float v = -2.0f * xp[(size_t)c * HW + hwb + tid];
            short h = f2bf(v);
            hv[j] = h;
            lv[j] = f2bf(v - bf2f(h));
        }
        int ks = cb >> 1, hb = cb & 1;
        ((s16x8*)shH)[(g * 5 + ks) * 64 + l5 + 32 * hb] = hv;
        ((s16x8*)shL)[(g * 4 + ks) * 64 + l5 + 32 * hb] = lv;
    }
    {   // ks=4: cols 64,65 = 1.0 (en pickup), rest 0
        s16x8 v0, z;
#pragma unroll
        for (int j = 0; j < 8; ++j) { v0[j] = 0; z[j] = 0; }
        v0[0] = (short)0x3F80; v0[1] = (short)0x3F80;
        ((s16x8*)shH)[(g * 5 + 4) * 64 + l5] = v0;
        ((s16x8*)shH)[(g * 5 + 4) * 64 + 32 + l5] = z;
    }
    __syncthreads();

    int wv = tid >> 6, lane = tid & 63;
    int ga = wv * 2, gb = wv * 2 + 1;
    const s16x8* sH8 = (const s16x8*)shH;
    const s16x8* sL8 = (const s16x8*)shL;
    s16x8 bh0[5], bh1[5], bl0[4], bl1[4];
#pragma unroll
    for (int ks = 0; ks < 5; ++ks) {
        bh0[ks] = sH8[(ga * 5 + ks) * 64 + lane];
        bh1[ks] = sH8[(gb * 5 + ks) * 64 + lane];
    }
#pragma unroll
    for (int ks = 0; ks < 4; ++ks) {
        bl0[ks] = sL8[(ga * 4 + ks) * 64 + lane];
        bl1[ks] = sL8[(gb * 4 + ks) * 64 + lane];
    }

    const s16x8* eh8 = (const s16x8*)ehf;
    const s16x8* el8 = (const s16x8*)elf;

    float s1a = 3.402823466e38f, s2a = 3.402823466e38f;
    float s1b = 3.402823466e38f, s2b = 3.402823466e38f;
    int i1a = 0, i2a = 0, i1b = 0, i2b = 0;
    int hv4 = (lane >> 5) * 4;

    for (int mt = 0; mt < 16; ++mt) {
        f32x16 acc0, acc1;
#pragma unroll
        for (int r = 0; r < 16; ++r) { acc0[r] = 0.0f; acc1[r] = 0.0f; }
#pragma unroll
        for (int ks = 0; ks < 5; ++ks) {
            s16x8 a = eh8[(mt * 5 + ks) * 64 + lane];
            acc0 = __builtin_amdgcn_mfma_f32_32x32x16_bf16(a, bh0[ks], acc0, 0, 0, 0);
            acc1 = __builtin_amdgcn_mfma_f32_32x32x16_bf16(a, bh1[ks], acc1, 0, 0, 0);
        }
#pragma unroll
        for (int ks = 0; ks < 4; ++ks) {
            s16x8 a = el8[(mt * 4 + ks) * 64 + lane];
            acc0 = __builtin_amdgcn_mfma_f32_32x32x16_bf16(a, bh0[ks], acc0, 0, 0, 0);
            acc1 = __builtin_amdgcn_mfma_f32_32x32x16_bf16(a, bh1[ks], acc1, 0, 0, 0);
        }
#pragma unroll
        for (int ks = 0; ks < 4; ++ks) {
            s16x8 a = eh8[(mt * 5 + ks) * 64 + lane];
            acc0 = __builtin_amdgcn_mfma_f32_32x32x16_bf16(a, bl0[ks], acc0, 0, 0, 0);
            acc1 = __builtin_amdgcn_mfma_f32_32x32x16_bf16(a, bl1[ks], acc1, 0, 0, 0);
        }
        int mb = mt * 32 + hv4;
#pragma unroll
        for (int r = 0; r < 16; ++r) {
            int mi = mb + (r & 3) + 8 * (r >> 2);
            {
                float s = acc0[r];
                bool c1 = s < s1a, c2 = s < s2a;
                s2a = c1 ? s1a : (c2 ? s : s2a); i2a = c1 ? i1a : (c2 ? mi : i2a);
                s1a = c1 ? s : s1a;              i1a = c1 ? mi : i1a;
            }
            {
                float s = acc1[r];
                bool c1 = s < s1b, c2 = s < s2b;
                s2b = c1 ? s1b : (c2 ? s : s2b); i2b = c1 ? i1b : (c2 ? mi : i2b);
                s1b = c1 ? s : s1b;              i1b = c1 ? mi : i1b;
            }
        }
    }

    // merge half-waves (disjoint m-sets) per group
    merge2(s1a, i1a, s2a, i2a, __shfl_xor(s1a, 32), __shfl_xor(i1a, 32),
           __shfl_xor(s2a, 32), __shfl_xor(i2a, 32));
    merge2(s1b, i1b, s2b, i2b, __shfl_xor(s1b, 32), __shfl_xor(i1b, 32),
           __shfl_xor(s2b, 32), __shfl_xor(i2b, 32));

    bool hi = (lane & 32) != 0;
    int I1 = hi ? i1b : i1a;
    int I2 = hi ? i2b : i2a;

    // ---- exact fp32 rescore of the two candidates (matches reference rounding) ----
    int tok_loc = wv * 64 + lane;
    int hw = hwb + tok_loc;
    const float* xq = xp + hw;
    float xv[64];
#pragma unroll
    for (int c = 0; c < 64; ++c) xv[c] = xq[(size_t)c * HW];

    float sxx;
    {
        float d0 = 0.f, d1 = 0.f, d2 = 0.f, d3 = 0.f;
#pragma unroll
        for (int c = 0; c < 64; c += 4) {
            d0 = fmaf(xv[c], xv[c], d0);
            d1 = fmaf(xv[c + 1], xv[c + 1], d1);
            d2 = fmaf(xv[c + 2], xv[c + 2], d2);
            d3 = fmaf(xv[c + 3], xv[c + 3], d3);
        }
        sxx = (d0 + d1) + (d2 + d3);
    }

    int ia = (I1 < I2) ? I1 : I2;
    int ib = (I1 < I2) ? I2 : I1;
    float sa, sb;
    {
        const float4* er = (const float4*)(emb + (size_t)ia * 64);
        float d0 = 0.f, d1 = 0.f, d2 = 0.f, d3 = 0.f;
#pragma unroll
        for (int q = 0; q < 16; ++q) {
            float4 e4 = er[q];
            d0 = fmaf(xv[q * 4], e4.x, d0);
            d1 = fmaf(xv[q * 4 + 1], e4.y, d1);
            d2 = fmaf(xv[q * 4 + 2], e4.z, d2);
            d3 = fmaf(xv[q * 4 + 3], e4.w, d3);
        }
        sa = (sxx + en[ia]) - 2.0f * ((d0 + d1) + (d2 + d3));
    }
    {
        const float4* er = (const float4*)(emb + (size_t)ib * 64);
        float d0 = 0.f, d1 = 0.f, d2 = 0.f, d3 = 0.f;
#pragma unroll
        for (int q = 0; q < 16; ++q) {
            float4 e4 = er[q];
            d0 = fmaf(xv[q * 4], e4.x, d0);
            d1 = fmaf(xv[q * 4 + 1], e4.y, d1);
            d2 = fmaf(xv[q * 4 + 2], e4.z, d2);
            d3 = fmaf(xv[q * 4 + 3], e4.w, d3);
        }
        sb = (sxx + en[ib]) - 2.0f * ((d0 + d1) + (d2 + d3));
    }
    int win = (sb < sa) ? ib : ia;   // ascending-scan first-min semantics

    idx_out[tb + tok_loc] = (unsigned short)win;

    // quantized write + loss
    const float4* ew = (const float4*)(emb + (size_t)win * 64);
    float* qp = qout + (size_t)n * 64 * HW + hw;
    float l0 = 0.f, l1 = 0.f, l2 = 0.f, l3 = 0.f;
#pragma unroll
    for (int q = 0; q < 16; ++q) {
        float4 e4 = ew[q];
        qp[(size_t)(q * 4) * HW] = e4.x;
        qp[(size_t)(q * 4 + 1) * HW] = e4.y;
        qp[(size_t)(q * 4 + 2) * HW] = e4.z;
        qp[(size_t)(q * 4 + 3) * HW] = e4.w;
        float f0 = xv[q * 4] - e4.x, f1 = xv[q * 4 + 1] - e4.y;
        float f2 = xv[q * 4 + 2] - e4.z, f3 = xv[q * 4 + 3] - e4.w;
        l0 = fmaf(f0, f0, l0);
        l1 = fmaf(f1, f1, l1);
        l2 = fmaf(f2, f2, l2);
        l3 = fmaf(f3, f3, l3);
    }
    float lp = (l0 + l1) + (l2 + l3);
#pragma unroll
    for (int off = 32; off; off >>= 1) lp += __shfl_down(lp, off);
    if ((tid & 63) == 0) atomicAdd(loss_acc, lp);
}

// grid = (32 images) x (8 channel-groups); LDS acc [512][9] (9 coprime to 32).
__global__ __launch_bounds__(1024) void k_seg(const float* __restrict__ x,
                                              const unsigned short* __restrict__ idx,
                                              float* __restrict__ cnt_g,
                                              float* __restrict__ avg_g) {
    __shared__ float acc[KC * 9];
    __shared__ float cnt[KC];
    int tid = threadIdx.x;
    int n = blockIdx.x >> 3;
    int cg = blockIdx.x & 7;

    for (int i = tid; i < KC * 9; i += 1024) acc[i] = 0.f;
    if (cg == 0 && tid < KC) cnt[tid] = 0.f;
    __syncthreads();

    const float* xp = x + (size_t)n * 64 * HW + (size_t)(cg * 8) * HW;
    const unsigned short* ip = idx + n * HW;

#pragma unroll
    for (int p = 0; p < 4; ++p) {
        int hw = p * 1024 + tid;
        int k = ip[hw];
        if (cg == 0) atomicAdd(&cnt[k], 1.0f);
        float* row = acc + k * 9;
#pragma unroll
        for (int j = 0; j < 8; ++j) {
            atomicAdd(&row[j], xp[(size_t)j * HW + hw]);
        }
    }
    __syncthreads();

    for (int i = tid; i < KC * 8; i += 1024) {
        int k = i >> 3, j = i & 7;
        atomicAdd(&avg_g[k * 64 + cg * 8 + j], acc[k * 9 + j]);
    }
    if (cg == 0 && tid < KC) atomicAdd(&cnt_g[tid], cnt[tid]);
}

__global__ void k_fin(const float* __restrict__ cs_in, const float* __restrict__ avg_in,
                      const float* __restrict__ cnt, const float* __restrict__ avgacc,
                      const float* __restrict__ loss_acc,
                      float* __restrict__ loss_out, float* __restrict__ emb_out,
                      float* __restrict__ cs_out, float* __restrict__ avg_out) {
    int i = blockIdx.x * 256 + threadIdx.x;
    if (i >= KC * 64) return;
    int k = i >> 6, c = i & 63;
    float ncs = cs_in[k] * 0.99f + 0.01f * cnt[k];
    float nav = avg_in[i] * 0.99f + 0.01f * avgacc[i];
    avg_out[i] = nav;
    emb_out[i] = nav / (ncs + 1e-5f);
    if (c == 0) cs_out[k] = ncs;
    if (i == 0) loss_out[0] = loss_acc[0] * (1.0f / 8388608.0f);
}

extern "C" void kernel_launch(void* const* d_in, const int* in_sizes, int n_in,
                              void* d_out, int out_size, void* d_ws, size_t ws_size,
                              hipStream_t stream) {
    (void)in_sizes; (void)n_in; (void)out_size; (void)ws_size;
    const float* x   = (const float*)d_in[0];
    const float* emb = (const float*)d_in[1];
    const float* cs  = (const float*)d_in[2];
    const float* avg = (const float*)d_in[3];

    float* out      = (float*)d_out;
    float* qout     = out;
    float* loss_out = out + 8388608;
    float* emb_out  = loss_out + 1;
    float* cs_out   = emb_out + 32768;
    float* avg_out  = cs_out + 512;

    char* wsb = (char*)d_ws;
    float* cnt_acc  = (float*)wsb;
    float* avg_acc  = (float*)(wsb + 2048);
    float* loss_acc = (float*)(wsb + 133120);
    float* en       = (float*)(wsb + WS_EN);
    short* ehf      = (short*)(wsb + WS_EHF);
    short* elf      = (short*)(wsb + WS_ELF);
    unsigned short* idx = (unsigned short*)(wsb + WS_IDX);

    hipMemsetAsync(d_ws, 0, 133124, stream);
    k_prep_en<<<2, 256, 0, stream>>>(emb, en);
    k_prep_frag<<<16, 256, 0, stream>>>(emb, en, ehf, elf);
    k_main<<<512, 256, 0, stream>>>(x, ehf, elf, en, emb, qout, idx, loss_acc);
    k_seg<<<256, 1024, 0, stream>>>(x, idx, cnt_acc, avg_acc);
    k_fin<<<128, 256, 0, stream>>>(cs, avg, cnt_acc, avg_acc, loss_acc,
                                   loss_out, emb_out, cs_out, avg_out);
}

// Round 5
// 157.988 us; speedup vs baseline: 1.7730x; 1.1385x over previous
//
#include <hip/hip_runtime.h>

#define HW 4096
#define KC 512

typedef __attribute__((ext_vector_type(8))) short s16x8;
typedef __attribute__((ext_vector_type(16))) float f32x16;

__device__ inline short f2bf(float f) {          // RTNE float->bf16
    unsigned int u = __builtin_bit_cast(unsigned int, f);
    unsigned int lsb = (u >> 16) & 1u;
    u += 0x7fffu + lsb;
    return (short)(u >> 16);
}
__device__ inline float bf2f(short h) {
    unsigned int u = ((unsigned int)(unsigned short)h) << 16;
    return __builtin_bit_cast(float, u);
}

// ws byte layout:
//   0       cnt f32[512]                  (zeroed)
//   2048    avg f32[32768]                (zeroed)
//   133120  loss f32[1]                   (zeroed)
//   133136  en f32[512]
//   135184  ehfrag short[16*5*64*8]  80KB (codes hi + en hi/lo cols, K=80)
//   217104  elfrag short[16*4*64*8]  64KB (codes lo, K=64)
//   282640  idx u16[131072]
#define WS_EN    133136
#define WS_EHF   135184
#define WS_ELF   217104
#define WS_IDX   282640

__global__ void k_prep_en(const float* __restrict__ emb, float* __restrict__ en) {
    int m = blockIdx.x * 256 + threadIdx.x;
    if (m >= KC) return;
    const float* e = emb + m * 64;
    float d0 = 0.f, d1 = 0.f, d2 = 0.f, d3 = 0.f;
#pragma unroll
    for (int c = 0; c < 64; c += 4) {
        d0 = fmaf(e[c], e[c], d0);
        d1 = fmaf(e[c + 1], e[c + 1], d1);
        d2 = fmaf(e[c + 2], e[c + 2], d2);
        d3 = fmaf(e[c + 3], e[c + 3], d3);
    }
    en[m] = (d0 + d1) + (d2 + d3);
}

// Build pre-swizzled A-fragments (32x32x16 layout: m=lane&31, k=(lane>>5)*8+j).
__global__ void k_prep_frag(const float* __restrict__ emb, const float* __restrict__ en,
                            short* __restrict__ ehf, short* __restrict__ elf) {
    int t = blockIdx.x * 256 + threadIdx.x;   // 0..4095
    int m = t >> 3, ko = t & 7;
    int mt = m >> 5, ks = ko >> 1;
    int lane = (m & 31) + 32 * (ko & 1);
    s16x8 hv, lv;
#pragma unroll
    for (int j = 0; j < 8; ++j) {
        float v = emb[m * 64 + ko * 8 + j];
        short h = f2bf(v);
        hv[j] = h;
        lv[j] = f2bf(v - bf2f(h));
    }
    ((s16x8*)ehf)[(mt * 5 + ks) * 64 + lane] = hv;
    ((s16x8*)elf)[(mt * 4 + ks) * 64 + lane] = lv;

    // ks=4 block of ehf: k=64 -> en_hi, k=65 -> en_lo, rest 0. One u32 per thread.
    int e2 = t * 2;
    int mt2 = e2 >> 9;
    int lane2 = (e2 >> 3) & 63;
    int j2 = e2 & 7;
    unsigned int val = 0;
    if (lane2 < 32 && j2 == 0) {
        float ev = en[mt2 * 32 + (lane2 & 31)];
        short eh_ = f2bf(ev);
        short el_ = f2bf(ev - bf2f(eh_));
        val = ((unsigned int)(unsigned short)eh_) | (((unsigned int)(unsigned short)el_) << 16);
    }
    *(unsigned int*)(ehf + ((size_t)(mt2 * 5 + 4) * 64 + lane2) * 8 + j2) = val;
}

__device__ inline void merge2(float& s1, int& i1, float& s2, int& i2,
                              float os1, int oi1, float os2, int oi2) {
    bool ob = (os1 < s1) || (os1 == s1 && oi1 < i1);
    float n1s = ob ? os1 : s1;  int n1i = ob ? oi1 : i1;
    float ls  = ob ? s1  : os1; int li  = ob ? i1  : oi1;  // losing first
    float ws  = ob ? os2 : s2;  int wi  = ob ? oi2 : i2;   // winner's second
    bool b2 = (ls < ws) || (ls == ws && li < wi);
    s1 = n1s; i1 = n1i;
    s2 = b2 ? ls : ws; i2 = b2 ? li : wi;
}

// 256 threads = 4 fully independent waves (no LDS, no barriers).
// Each wave: 64 tokens x 512 codes. B-fragments of x~ = -2x (hi/lo bf16 split)
// are loaded DIRECTLY from global in MFMA fragment order:
//   frag_a: token wbase+(lane&31),    channel ks*16+(lane>>5)*8+j
//   frag_b: token wbase+32+(lane&31), same channels
// score_rel = en - 2*x.e via 13 MFMA/tile; top-2 tracked; exact fp32 rescore.
__global__ __launch_bounds__(256) void k_main(const float* __restrict__ x,
                                              const short* __restrict__ ehf,
                                              const short* __restrict__ elf,
                                              const float* __restrict__ en,
                                              const float* __restrict__ emb,
                                              float* __restrict__ qout,
                                              unsigned short* __restrict__ idx_out,
                                              float* __restrict__ loss_acc) {
    int tid = threadIdx.x;
    int wv = tid >> 6, lane = tid & 63;
    int tb = blockIdx.x * 256;
    int n = tb >> 12, hwb = tb & 4095;
    const float* xp = x + (size_t)n * 64 * HW;
    int wbase = hwb + wv * 64;

    int l5 = lane & 31;
    int kh = (lane >> 5) * 8;    // k-half channel offset

    // ---- direct-to-fragment loads of x~ (hi/lo bf16) ----
    s16x8 fah[5], fbh[5], fal[4], fbl[4];
    {
        const float* pa = xp + wbase + l5;
        const float* pb = pa + 32;
#pragma unroll
        for (int ks = 0; ks < 4; ++ks) {
            s16x8 ha, la, hb, lb;
#pragma unroll
            for (int j = 0; j < 8; ++j) {
                int c = ks * 16 + kh + j;
                float va = -2.0f * pa[(size_t)c * HW];
                float vb = -2.0f * pb[(size_t)c * HW];
                short h0 = f2bf(va); ha[j] = h0; la[j] = f2bf(va - bf2f(h0));
                short h1 = f2bf(vb); hb[j] = h1; lb[j] = f2bf(vb - bf2f(h1));
            }
            fah[ks] = ha; fal[ks] = la; fbh[ks] = hb; fbl[ks] = lb;
        }
        s16x8 v0;
#pragma unroll
        for (int j = 0; j < 8; ++j) v0[j] = 0;
        if (lane < 32) { v0[0] = (short)0x3F80; v0[1] = (short)0x3F80; }
        fah[4] = v0; fbh[4] = v0;
    }

    const s16x8* eh8 = (const s16x8*)ehf;
    const s16x8* el8 = (const s16x8*)elf;

    float s1a = 3.402823466e38f, s2a = 3.402823466e38f;
    float s1b = 3.402823466e38f, s2b = 3.402823466e38f;
    int i1a = 0, i2a = 0, i1b = 0, i2b = 0;
    int hv4 = (lane >> 5) * 4;

#pragma unroll 2
    for (int mt = 0; mt < 16; ++mt) {
        s16x8 ah[5], al[4];
#pragma unroll
        for (int ks = 0; ks < 5; ++ks) ah[ks] = eh8[(mt * 5 + ks) * 64 + lane];
#pragma unroll
        for (int ks = 0; ks < 4; ++ks) al[ks] = el8[(mt * 4 + ks) * 64 + lane];

        f32x16 acc0, acc1;
#pragma unroll
        for (int r = 0; r < 16; ++r) { acc0[r] = 0.0f; acc1[r] = 0.0f; }
#pragma unroll
        for (int ks = 0; ks < 5; ++ks) {
            acc0 = __builtin_amdgcn_mfma_f32_32x32x16_bf16(ah[ks], fah[ks], acc0, 0, 0, 0);
            acc1 = __builtin_amdgcn_mfma_f32_32x32x16_bf16(ah[ks], fbh[ks], acc1, 0, 0, 0);
        }
#pragma unroll
        for (int ks = 0; ks < 4; ++ks) {
            acc0 = __builtin_amdgcn_mfma_f32_32x32x16_bf16(al[ks], fah[ks], acc0, 0, 0, 0);
            acc1 = __builtin_amdgcn_mfma_f32_32x32x16_bf16(al[ks], fbh[ks], acc1, 0, 0, 0);
        }
#pragma unroll
        for (int ks = 0; ks < 4; ++ks) {
            acc0 = __builtin_amdgcn_mfma_f32_32x32x16_bf16(ah[ks], fal[ks], acc0, 0, 0, 0);
            acc1 = __builtin_amdgcn_mfma_f32_32x32x16_bf16(ah[ks], fbl[ks], acc1, 0, 0, 0);
        }

        int mb = mt * 32 + hv4;
#pragma unroll
        for (int r = 0; r < 16; ++r) {
            int mi = mb + (r & 3) + 8 * (r >> 2);
            {
                float s = acc0[r];
                bool c1 = s < s1a, c2 = s < s2a;
                s2a = c1 ? s1a : (c2 ? s : s2a); i2a = c1 ? i1a : (c2 ? mi : i2a);
                s1a = c1 ? s : s1a;              i1a = c1 ? mi : i1a;
            }
            {
                float s = acc1[r];
                bool c1 = s < s1b, c2 = s < s2b;
                s2b = c1 ? s1b : (c2 ? s : s2b); i2b = c1 ? i1b : (c2 ? mi : i2b);
                s1b = c1 ? s : s1b;              i1b = c1 ? mi : i1b;
            }
        }
    }

    // lanes l and l^32 hold disjoint code-rows of the same token column: merge
    merge2(s1a, i1a, s2a, i2a, __shfl_xor(s1a, 32), __shfl_xor(i1a, 32),
           __shfl_xor(s2a, 32), __shfl_xor(i2a, 32));
    merge2(s1b, i1b, s2b, i2b, __shfl_xor(s1b, 32), __shfl_xor(i1b, 32),
           __shfl_xor(s2b, 32), __shfl_xor(i2b, 32));

    bool hi = (lane & 32) != 0;
    int I1 = hi ? i1b : i1a;
    int I2 = hi ? i2b : i2a;

    // ---- exact fp32 rescore of the two candidates (matches reference rounding) ----
    int hw = wbase + lane;                 // == hwb + tid
    const float* xq = xp + hw;
    float xv[64];
#pragma unroll
    for (int c = 0; c < 64; ++c) xv[c] = xq[(size_t)c * HW];

    float sxx;
    {
        float d0 = 0.f, d1 = 0.f, d2 = 0.f, d3 = 0.f;
#pragma unroll
        for (int c = 0; c < 64; c += 4) {
            d0 = fmaf(xv[c], xv[c], d0);
            d1 = fmaf(xv[c + 1], xv[c + 1], d1);
            d2 = fmaf(xv[c + 2], xv[c + 2], d2);
            d3 = fmaf(xv[c + 3], xv[c + 3], d3);
        }
        sxx = (d0 + d1) + (d2 + d3);
    }

    int ia = (I1 < I2) ? I1 : I2;
    int ib = (I1 < I2) ? I2 : I1;
    float sa, sb;
    {
        const float4* er = (const float4*)(emb + (size_t)ia * 64);
        float d0 = 0.f, d1 = 0.f, d2 = 0.f, d3 = 0.f;
#pragma unroll
        for (int q = 0; q < 16; ++q) {
            float4 e4 = er[q];
            d0 = fmaf(xv[q * 4], e4.x, d0);
            d1 = fmaf(xv[q * 4 + 1], e4.y, d1);
            d2 = fmaf(xv[q * 4 + 2], e4.z, d2);
            d3 = fmaf(xv[q * 4 + 3], e4.w, d3);
        }
        sa = (sxx + en[ia]) - 2.0f * ((d0 + d1) + (d2 + d3));
    }
    {
        const float4* er = (const float4*)(emb + (size_t)ib * 64);
        float d0 = 0.f, d1 = 0.f, d2 = 0.f, d3 = 0.f;
#pragma unroll
        for (int q = 0; q < 16; ++q) {
            float4 e4 = er[q];
            d0 = fmaf(xv[q * 4], e4.x, d0);
            d1 = fmaf(xv[q * 4 + 1], e4.y, d1);
            d2 = fmaf(xv[q * 4 + 2], e4.z, d2);
            d3 = fmaf(xv[q * 4 + 3], e4.w, d3);
        }
        sb = (sxx + en[ib]) - 2.0f * ((d0 + d1) + (d2 + d3));
    }
    int win = (sb < sa) ? ib : ia;   // tie -> lower index (ia < ib)

    idx_out[tb + wv * 64 + lane] = (unsigned short)win;

    // quantized write + loss
    const float4* ew = (const float4*)(emb + (size_t)win * 64);
    float* qp = qout + (size_t)n * 64 * HW + hw;
    float l0 = 0.f, l1 = 0.f, l2 = 0.f, l3 = 0.f;
#pragma unroll
    for (int q = 0; q < 16; ++q) {
        float4 e4 = ew[q];
        qp[(size_t)(q * 4) * HW] = e4.x;
        qp[(size_t)(q * 4 + 1) * HW] = e4.y;
        qp[(size_t)(q * 4 + 2) * HW] = e4.z;
        qp[(size_t)(q * 4 + 3) * HW] = e4.w;
        float f0 = xv[q * 4] - e4.x, f1 = xv[q * 4 + 1] - e4.y;
        float f2 = xv[q * 4 + 2] - e4.z, f3 = xv[q * 4 + 3] - e4.w;
        l0 = fmaf(f0, f0, l0);
        l1 = fmaf(f1, f1, l1);
        l2 = fmaf(f2, f2, l2);
        l3 = fmaf(f3, f3, l3);
    }
    float lp = (l0 + l1) + (l2 + l3);
#pragma unroll
    for (int off = 32; off; off >>= 1) lp += __shfl_down(lp, off);
    if (lane == 0) atomicAdd(loss_acc, lp);
}

// grid = (32 images) x (8 channel-groups); LDS acc [512][9] (9 coprime to 32).
__global__ __launch_bounds__(1024) void k_seg(const float* __restrict__ x,
                                              const unsigned short* __restrict__ idx,
                                              float* __restrict__ cnt_g,
                                              float* __restrict__ avg_g) {
    __shared__ float acc[KC * 9];
    __shared__ float cnt[KC];
    int tid = threadIdx.x;
    int n = blockIdx.x >> 3;
    int cg = blockIdx.x & 7;

    for (int i = tid; i < KC * 9; i += 1024) acc[i] = 0.f;
    if (cg == 0 && tid < KC) cnt[tid] = 0.f;
    __syncthreads();

    const float* xp = x + (size_t)n * 64 * HW + (size_t)(cg * 8) * HW;
    const unsigned short* ip = idx + n * HW;

#pragma unroll
    for (int p = 0; p < 4; ++p) {
        int hw = p * 1024 + tid;
        int k = ip[hw];
        if (cg == 0) atomicAdd(&cnt[k], 1.0f);
        float* row = acc + k * 9;
#pragma unroll
        for (int j = 0; j < 8; ++j) {
            atomicAdd(&row[j], xp[(size_t)j * HW + hw]);
        }
    }
    __syncthreads();

    for (int i = tid; i < KC * 8; i += 1024) {
        int k = i >> 3, j = i & 7;
        atomicAdd(&avg_g[k * 64 + cg * 8 + j], acc[k * 9 + j]);
    }
    if (cg == 0 && tid < KC) atomicAdd(&cnt_g[tid], cnt[tid]);
}

__global__ void k_fin(const float* __restrict__ cs_in, const float* __restrict__ avg_in,
                      const float* __restrict__ cnt, const float* __restrict__ avgacc,
                      const float* __restrict__ loss_acc,
                      float* __restrict__ loss_out, float* __restrict__ emb_out,
                      float* __restrict__ cs_out, float* __restrict__ avg_out) {
    int i = blockIdx.x * 256 + threadIdx.x;
    if (i >= KC * 64) return;
    int k = i >> 6, c = i & 63;
    float ncs = cs_in[k] * 0.99f + 0.01f * cnt[k];
    float nav = avg_in[i] * 0.99f + 0.01f * avgacc[i];
    avg_out[i] = nav;
    emb_out[i] = nav / (ncs + 1e-5f);
    if (c == 0) cs_out[k] = ncs;
    if (i == 0) loss_out[0] = loss_acc[0] * (1.0f / 8388608.0f);
}

extern "C" void kernel_launch(void* const* d_in, const int* in_sizes, int n_in,
                              void* d_out, int out_size, void* d_ws, size_t ws_size,
                              hipStream_t stream) {
    (void)in_sizes; (void)n_in; (void)out_size; (void)ws_size;
    const float* x   = (const float*)d_in[0];
    const float* emb = (const float*)d_in[1];
    const float* cs  = (const float*)d_in[2];
    const float* avg = (const float*)d_in[3];

    float* out      = (float*)d_out;
    float* qout     = out;
    float* loss_out = out + 8388608;
    float* emb_out  = loss_out + 1;
    float* cs_out   = emb_out + 32768;
    float* avg_out  = cs_out + 512;

    char* wsb = (char*)d_ws;
    float* cnt_acc  = (float*)wsb;
    float* avg_acc  = (float*)(wsb + 2048);
    float* loss_acc = (float*)(wsb + 133120);
    float* en       = (float*)(wsb + WS_EN);
    short* ehf      = (short*)(wsb + WS_EHF);
    short* elf      = (short*)(wsb + WS_ELF);
    unsigned short* idx = (unsigned short*)(wsb + WS_IDX);

    hipMemsetAsync(d_ws, 0, 133124, stream);
    k_prep_en<<<2, 256, 0, stream>>>(emb, en);
    k_prep_frag<<<16, 256, 0, stream>>>(emb, en, ehf, elf);
    k_main<<<512, 256, 0, stream>>>(x, ehf, elf, en, emb, qout, idx, loss_acc);
    k_seg<<<256, 1024, 0, stream>>>(x, idx, cnt_acc, avg_acc);
    k_fin<<<128, 256, 0, stream>>>(cs, avg, cnt_acc, avg_acc, loss_acc,
                                   loss_out, emb_out, cs_out, avg_out);
}